// Round 3
// baseline (380.537 us; speedup 1.0000x reference)
//
#include <hip/hip_runtime.h>

// RAVNet ragged attention, split bf16-MFMA design.
// K-A: per-wave QKV projection (no LDS/barriers) -> ws.  K-B: per-wave
// (group, q-tile) attention units (no barriers; per-wave LDS scratch only).

typedef __attribute__((ext_vector_type(8))) short short8;   // 8 bf16
typedef __attribute__((ext_vector_type(4))) float f32x4;
typedef __attribute__((ext_vector_type(4))) short short4v;

constexpr int C  = 81;
constexpr int DK = 64;
constexpr int CP = 96;              // C padded to 3*32
constexpr int P_STRIDE = 136;       // P scratch row stride (ushorts)
constexpr int O_STRIDE = 72;        // O scratch row stride

__device__ inline ushort f2b(float f) {   // fp32 -> bf16 bits, RNE
    uint u = __float_as_uint(f);
    return (ushort)((u + 0x7fffu + ((u >> 16) & 1u)) >> 16);
}

#define MFMA16(a, b, c) __builtin_amdgcn_mfma_f32_16x16x32_bf16((a), (b), (c), 0, 0, 0)

// ---------- Kernel 1: scans + work-unit map ----------
// off[g]=flat x row offset; umap[u]=(g<<3)|local_tile for every 16-row tile.
__global__ void scan_build(const int* __restrict__ counts, int n,
                           int* __restrict__ off, uint* __restrict__ umap,
                           int* __restrict__ totals) {
    __shared__ int pc[256], pu[256];
    int tid = threadIdx.x;
    int per = (n + 255) >> 8;
    int base = tid * per;
    int sc = 0, su = 0;
    for (int i = 0; i < per; i++) {
        int idx = base + i;
        if (idx < n) { int c = counts[idx]; sc += c; su += (c + 15) >> 4; }
    }
    pc[tid] = sc; pu[tid] = su;
    __syncthreads();
    for (int o = 1; o < 256; o <<= 1) {
        int vc = (tid >= o) ? pc[tid - o] : 0;
        int vu = (tid >= o) ? pu[tid - o] : 0;
        __syncthreads();
        pc[tid] += vc; pu[tid] += vu;
        __syncthreads();
    }
    int runc = tid ? pc[tid - 1] : 0;
    int runu = tid ? pu[tid - 1] : 0;
    for (int i = 0; i < per; i++) {
        int idx = base + i;
        if (idx < n) {
            int c = counts[idx];
            int nt = (c + 15) >> 4;
            off[idx] = runc;
            for (int lt = 0; lt < nt; lt++) umap[runu + lt] = ((uint)idx << 3) | lt;
            runc += c; runu += nt;
        }
    }
    if (tid == 0) { off[n] = pc[255]; totals[0] = pu[255]; }
}

// ---------- Kernel 2: weights -> bf16 transposed ----------
__global__ void prep_weights(const float* __restrict__ prior,
                             const float* __restrict__ wq, const float* __restrict__ wk,
                             const float* __restrict__ wv, const float* __restrict__ wu,
                             ushort* __restrict__ wqT, ushort* __restrict__ wkT,
                             ushort* __restrict__ wvT, ushort* __restrict__ wuT) {
    int idx = blockIdx.x * 256 + threadIdx.x;
    int sec = idx / (DK * CP);
    int i   = idx - sec * (DK * CP);
    if (sec == 0 || sec == 1) {
        int nn = i / CP, k = i - (i / CP) * CP;
        const float* w = (sec == 0) ? wq : wk;
        ushort* dst    = (sec == 0) ? wqT : wkT;
        dst[nn * CP + k] = (k < C) ? f2b(w[k * DK + nn]) : (ushort)0;
    } else if (sec == 2) {
        int nn = i / CP, k = i - (i / CP) * CP;
        float s = 0.f;
        if (k < C)
            for (int e = 0; e < C; e++) s = fmaf(prior[k * C + e], wv[e * DK + nn], s);
        wvT[nn * CP + k] = (k < C) ? f2b(s) : (ushort)0;
    } else {
        int nn = i / DK, k = i - (i / DK) * DK;
        wuT[nn * DK + k] = (nn < C) ? f2b(wu[k * C + nn]) : (ushort)0;
    }
}

// ---------- Kernel 3: QKV projection, one wave per 16-row padded tile ----------
__launch_bounds__(256, 6)
__global__ void qkv_proj(const float* __restrict__ x,
                         const int* __restrict__ counts, const int* __restrict__ off,
                         const uint* __restrict__ umap, const int* __restrict__ totals,
                         const ushort* __restrict__ wqT, const ushort* __restrict__ wkT,
                         const ushort* __restrict__ wvT,
                         const float* __restrict__ bq, const float* __restrict__ bk,
                         const float* __restrict__ bv,
                         ushort* __restrict__ Qg, ushort* __restrict__ Kg,
                         ushort* __restrict__ VTg, int TPalloc) {
    const int u = blockIdx.x * 4 + (threadIdx.x >> 6);
    if (u >= totals[0]) return;
    const uint e = umap[u];
    const int g = e >> 3, lt = e & 7;
    const int N = counts[g];
    const int lane = threadIdx.x & 63;
    const int quad = lane >> 4, m16 = lane & 15;
    const int row  = lt * 16 + m16;          // local row in group
    const bool rv  = row < N;
    const float* xrow = x + ((long)off[g] + row) * C;

    // A-fragments: x[row][ks*32+quad*8 .. +7], fp32 -> bf16
    short8 afr[3];
    #pragma unroll
    for (int ks = 0; ks < 3; ks++) {
        short8 a;
        #pragma unroll
        for (int j = 0; j < 8; j++) {
            int c = ks * 32 + quad * 8 + j;
            float v = (rv && c < C) ? xrow[c] : 0.f;
            a[j] = (short)f2b(v);
        }
        afr[ks] = a;
    }

    const ushort* Ws[3] = {wqT, wkT, wvT};
    const float*  Bs[3] = {bq, bk, bv};
    const long prow0 = (long)u * 16;
    #pragma unroll
    for (int mat = 0; mat < 3; mat++) {
        const ushort* wT = Ws[mat];
        #pragma unroll
        for (int ct = 0; ct < 4; ct++) {
            const int nn = ct * 16 + m16;
            f32x4 acc = {0.f, 0.f, 0.f, 0.f};
            #pragma unroll
            for (int ks = 0; ks < 3; ks++) {
                short8 bfr = *(const short8*)(wT + nn * CP + ks * 32 + quad * 8);
                acc = MFMA16(afr[ks], bfr, acc);
            }
            float bval = Bs[mat][nn];
            if (mat < 2) {           // Q/K row-major: col=nn, rows=quad*4+r
                ushort* dst = (mat == 0) ? Qg : Kg;
                #pragma unroll
                for (int r = 0; r < 4; r++)
                    dst[(prow0 + quad * 4 + r) * DK + nn] = f2b(acc[r] + bval);
            } else {                 // V transposed: VT[dim][padded row]
                short4v pk;
                #pragma unroll
                for (int r = 0; r < 4; r++) pk[r] = (short)f2b(acc[r] + bval);
                *(short4v*)(VTg + (long)nn * TPalloc + prow0 + quad * 4) = pk;
            }
        }
    }
}

// ---------- Kernel 4: attention, one wave per (group, q-tile) unit ----------
__launch_bounds__(256, 5)
__global__ void attn(const int* __restrict__ counts, const int* __restrict__ off,
                     const uint* __restrict__ umap, const int* __restrict__ totals,
                     const ushort* __restrict__ Qg, const ushort* __restrict__ Kg,
                     const ushort* __restrict__ VTg, int TPalloc,
                     const ushort* __restrict__ wuT,
                     const float* __restrict__ bu, float* __restrict__ out) {
    __shared__ __align__(16) ushort sm[4 * (16 * P_STRIDE + 16 * O_STRIDE)]; // 26.6 KB
    const int wave = threadIdx.x >> 6;
    const int u = blockIdx.x * 4 + wave;
    if (u >= totals[0]) return;
    const uint en = umap[u];
    const int g = en >> 3, qt = en & 7;
    const int N = counts[g];
    const long g16 = (long)(u - qt) * 16;      // group's padded row base
    const int lane = threadIdx.x & 63;
    const int quad = lane >> 4, m16 = lane & 15;
    const int NT8 = (N + 15) >> 4;
    const int NT4 = (N + 31) >> 5;

    // Q A-fragments for this tile's 16 rows
    short8 aq[2];
    #pragma unroll
    for (int ks = 0; ks < 2; ks++)
        aq[ks] = *(const short8*)(Qg + ((long)u * 16 + m16) * DK + ks * 32 + quad * 8);

    // S = Q K^T, full row-block in registers (C-layout)
    f32x4 sacc[8];
    #pragma unroll
    for (int ct = 0; ct < 8; ct++) if (ct < NT8) {
        f32x4 a = {0.f, 0.f, 0.f, 0.f};
        #pragma unroll
        for (int ks = 0; ks < 2; ks++) {
            short8 kb = *(const short8*)(Kg + (g16 + ct * 16 + m16) * DK +
                                         ks * 32 + quad * 8);
            a = MFMA16(aq[ks], kb, a);
        }
        sacc[ct] = a;
    }
    // scale + key mask + row max/sum (rows in quads; reduce across m16)
    float mr[4] = {-3e38f, -3e38f, -3e38f, -3e38f};
    #pragma unroll
    for (int ct = 0; ct < 8; ct++) if (ct < NT8) {
        bool valid = (ct * 16 + m16) < N;
        #pragma unroll
        for (int r = 0; r < 4; r++) {
            float s = valid ? sacc[ct][r] * 0.125f : -3e38f;
            sacc[ct][r] = s;
            mr[r] = fmaxf(mr[r], s);
        }
    }
    #pragma unroll
    for (int r = 0; r < 4; r++) {
        mr[r] = fmaxf(mr[r], __shfl_xor(mr[r], 1, 64));
        mr[r] = fmaxf(mr[r], __shfl_xor(mr[r], 2, 64));
        mr[r] = fmaxf(mr[r], __shfl_xor(mr[r], 4, 64));
        mr[r] = fmaxf(mr[r], __shfl_xor(mr[r], 8, 64));
    }
    float lr[4] = {0.f, 0.f, 0.f, 0.f};
    #pragma unroll
    for (int ct = 0; ct < 8; ct++) if (ct < NT8) {
        #pragma unroll
        for (int r = 0; r < 4; r++) {
            float p = __expf(sacc[ct][r] - mr[r]);
            sacc[ct][r] = p;
            lr[r] += p;
        }
    }
    #pragma unroll
    for (int r = 0; r < 4; r++) {
        lr[r] += __shfl_xor(lr[r], 1, 64);
        lr[r] += __shfl_xor(lr[r], 2, 64);
        lr[r] += __shfl_xor(lr[r], 4, 64);
        lr[r] += __shfl_xor(lr[r], 8, 64);
    }
    // P: C-layout -> LDS -> A-fragments (per-wave scratch, no barrier)
    ushort* P = sm + wave * (16 * P_STRIDE);
    #pragma unroll
    for (int ct = 0; ct < 8; ct++) if (ct < NT8) {
        #pragma unroll
        for (int r = 0; r < 4; r++)
            P[(quad * 4 + r) * P_STRIDE + ct * 16 + m16] = f2b(sacc[ct][r]);
    }
    if (NT8 & 1) {
        #pragma unroll
        for (int r = 0; r < 4; r++)
            P[(quad * 4 + r) * P_STRIDE + NT8 * 16 + m16] = 0;
    }
    __threadfence_block();
    short8 ap[4];
    #pragma unroll
    for (int kt = 0; kt < 4; kt++) if (kt < NT4)
        ap[kt] = *(const short8*)(P + m16 * P_STRIDE + kt * 32 + quad * 8);

    // O = P V (B-fragments straight from global VT), normalize, stash bf16
    float linv[4];
    #pragma unroll
    for (int r = 0; r < 4; r++) linv[r] = (lr[r] > 0.f) ? 1.f / lr[r] : 0.f;
    ushort* O = sm + 4 * (16 * P_STRIDE) + wave * (16 * O_STRIDE);
    #pragma unroll
    for (int ot = 0; ot < 4; ot++) {
        f32x4 oa = {0.f, 0.f, 0.f, 0.f};
        #pragma unroll
        for (int kt = 0; kt < 4; kt++) if (kt < NT4) {
            short8 vb = *(const short8*)(VTg + (long)(ot * 16 + m16) * TPalloc +
                                         g16 + kt * 32 + quad * 8);
            oa = MFMA16(ap[kt], vb, oa);
        }
        #pragma unroll
        for (int r = 0; r < 4; r++)
            O[(quad * 4 + r) * O_STRIDE + ot * 16 + m16] = f2b(oa[r] * linv[r]);
    }
    __threadfence_block();
    short8 ao[2];
    #pragma unroll
    for (int ks = 0; ks < 2; ks++)
        ao[ks] = *(const short8*)(O + m16 * O_STRIDE + ks * 32 + quad * 8);

    // out = O @ Wu + bu, masked scatter
    const long obase = (long)off[g] * C;
    #pragma unroll
    for (int ct = 0; ct < 6; ct++) {
        f32x4 acc = {0.f, 0.f, 0.f, 0.f};
        #pragma unroll
        for (int ks = 0; ks < 2; ks++) {
            short8 wb = *(const short8*)(wuT + (ct * 16 + m16) * DK + ks * 32 + quad * 8);
            acc = MFMA16(ao[ks], wb, acc);
        }
        int e = ct * 16 + m16;
        if (e < C) {
            float bue = bu[e];
            #pragma unroll
            for (int r = 0; r < 4; r++) {
                int row = qt * 16 + quad * 4 + r;
                if (row < N) out[obase + (long)row * C + e] = acc[r] + bue;
            }
        }
    }
}

// ---------- launch ----------
extern "C" void kernel_launch(void* const* d_in, const int* in_sizes, int n_in,
                              void* d_out, int out_size, void* d_ws, size_t ws_size,
                              hipStream_t stream) {
    const float* x      = (const float*)d_in[0];
    const int*   counts = (const int*)  d_in[1];
    const float* prior  = (const float*)d_in[2];
    const float* wq     = (const float*)d_in[3];
    const float* bq     = (const float*)d_in[4];
    const float* wk     = (const float*)d_in[5];
    const float* bk     = (const float*)d_in[6];
    const float* wv     = (const float*)d_in[7];
    const float* bv     = (const float*)d_in[8];
    const float* wu     = (const float*)d_in[9];
    const float* bu     = (const float*)d_in[10];
    float* out = (float*)d_out;

    const int B     = in_sizes[1];
    const int total = in_sizes[0] / C;
    const int umax  = (total + 15 * B + 15) / 16;    // upper bound on Σceil(N/16)
    const int TPalloc = ((umax * 16 + 32 + 15) / 16) * 16;

    char* p = (char*)d_ws;
    auto alloc = [&](size_t bytes) {
        void* r = (void*)p;
        p += (bytes + 255) & ~(size_t)255;
        return r;
    };
    int*    off    = (int*)   alloc((size_t)(B + 1) * 4);
    int*    totals = (int*)   alloc(4);
    uint*   umap   = (uint*)  alloc((size_t)umax * 4);
    ushort* wqT    = (ushort*)alloc((size_t)DK * CP * 2);
    ushort* wkT    = (ushort*)alloc((size_t)DK * CP * 2);
    ushort* wvT    = (ushort*)alloc((size_t)DK * CP * 2);
    ushort* wuT    = (ushort*)alloc((size_t)CP * DK * 2);
    ushort* Qg     = (ushort*)alloc((size_t)umax * 16 * DK * 2);
    ushort* Kg     = (ushort*)alloc((size_t)umax * 16 * DK * 2);
    ushort* VTg    = (ushort*)alloc((size_t)DK * TPalloc * 2);

    const int ublocks = (umax + 3) / 4;

    scan_build<<<1, 256, 0, stream>>>(counts, B, off, umap, totals);
    prep_weights<<<(4 * DK * CP + 255) / 256, 256, 0, stream>>>(
        prior, wq, wk, wv, wu, wqT, wkT, wvT, wuT);
    qkv_proj<<<ublocks, 256, 0, stream>>>(x, counts, off, umap, totals,
                                          wqT, wkT, wvT, bq, bk, bv,
                                          Qg, Kg, VTg, TPalloc);
    attn<<<ublocks, 256, 0, stream>>>(counts, off, umap, totals,
                                      Qg, Kg, VTg, TPalloc, wuT, bu, out);
}

// Round 4
// 356.751 us; speedup vs baseline: 1.0667x; 1.0667x over previous
//
#include <hip/hip_runtime.h>

// RAVNet ragged attention, split bf16-MFMA design, round 4.
// qkv_proj: block-level coalesced LDS staging of x + operand-swapped Q/K
// MFMAs so all global stores are vectorized. attn unchanged from round 3.

typedef __attribute__((ext_vector_type(8))) short short8;   // 8 bf16
typedef __attribute__((ext_vector_type(4))) float f32x4;
typedef __attribute__((ext_vector_type(4))) short short4v;

constexpr int C  = 81;
constexpr int DK = 64;
constexpr int CP = 96;              // C padded to 3*32
constexpr int XQ_STRIDE = 104;      // LDS x-tile row stride (ushorts, 16B-mult)
constexpr int P_STRIDE = 136;       // attn P scratch row stride (ushorts)
constexpr int O_STRIDE = 72;        // attn O scratch row stride

__device__ inline ushort f2b(float f) {   // fp32 -> bf16 bits, RNE
    uint u = __float_as_uint(f);
    return (ushort)((u + 0x7fffu + ((u >> 16) & 1u)) >> 16);
}

#define MFMA16(a, b, c) __builtin_amdgcn_mfma_f32_16x16x32_bf16((a), (b), (c), 0, 0, 0)

// ---------- Kernel 1: scans + work-unit map ----------
__global__ void scan_build(const int* __restrict__ counts, int n,
                           int* __restrict__ off, uint* __restrict__ umap,
                           int* __restrict__ totals) {
    __shared__ int pc[256], pu[256];
    int tid = threadIdx.x;
    int per = (n + 255) >> 8;
    int base = tid * per;
    int sc = 0, su = 0;
    for (int i = 0; i < per; i++) {
        int idx = base + i;
        if (idx < n) { int c = counts[idx]; sc += c; su += (c + 15) >> 4; }
    }
    pc[tid] = sc; pu[tid] = su;
    __syncthreads();
    for (int o = 1; o < 256; o <<= 1) {
        int vc = (tid >= o) ? pc[tid - o] : 0;
        int vu = (tid >= o) ? pu[tid - o] : 0;
        __syncthreads();
        pc[tid] += vc; pu[tid] += vu;
        __syncthreads();
    }
    int runc = tid ? pc[tid - 1] : 0;
    int runu = tid ? pu[tid - 1] : 0;
    for (int i = 0; i < per; i++) {
        int idx = base + i;
        if (idx < n) {
            int c = counts[idx];
            int nt = (c + 15) >> 4;
            off[idx] = runc;
            for (int lt = 0; lt < nt; lt++) umap[runu + lt] = ((uint)idx << 3) | lt;
            runc += c; runu += nt;
        }
    }
    if (tid == 0) { off[n] = pc[255]; totals[0] = pu[255]; }
}

// ---------- Kernel 2: weights -> bf16 transposed ----------
__global__ void prep_weights(const float* __restrict__ prior,
                             const float* __restrict__ wq, const float* __restrict__ wk,
                             const float* __restrict__ wv, const float* __restrict__ wu,
                             ushort* __restrict__ wqT, ushort* __restrict__ wkT,
                             ushort* __restrict__ wvT, ushort* __restrict__ wuT) {
    int idx = blockIdx.x * 256 + threadIdx.x;
    int sec = idx / (DK * CP);
    int i   = idx - sec * (DK * CP);
    if (sec == 0 || sec == 1) {
        int nn = i / CP, k = i - (i / CP) * CP;
        const float* w = (sec == 0) ? wq : wk;
        ushort* dst    = (sec == 0) ? wqT : wkT;
        dst[nn * CP + k] = (k < C) ? f2b(w[k * DK + nn]) : (ushort)0;
    } else if (sec == 2) {
        int nn = i / CP, k = i - (i / CP) * CP;
        float s = 0.f;
        if (k < C)
            for (int e = 0; e < C; e++) s = fmaf(prior[k * C + e], wv[e * DK + nn], s);
        wvT[nn * CP + k] = (k < C) ? f2b(s) : (ushort)0;
    } else {
        int nn = i / DK, k = i - (i / DK) * DK;
        wuT[nn * DK + k] = (nn < C) ? f2b(wu[k * C + nn]) : (ushort)0;
    }
}

// ---------- Kernel 3: QKV projection ----------
// Block of 4 waves = 4 consecutive 16-row tiles; the valid source rows of a
// block form one contiguous flat range of x -> coalesced LDS staging.
__global__ void qkv_proj(const float* __restrict__ x,
                         const int* __restrict__ counts, const int* __restrict__ off,
                         const uint* __restrict__ umap, const int* __restrict__ totals,
                         const ushort* __restrict__ wqT, const ushort* __restrict__ wkT,
                         const ushort* __restrict__ wvT,
                         const float* __restrict__ bq, const float* __restrict__ bk,
                         const float* __restrict__ bv,
                         ushort* __restrict__ Qg, ushort* __restrict__ Kg,
                         ushort* __restrict__ VTg, int TPalloc) {
    __shared__ __align__(16) ushort xls[64 * XQ_STRIDE];   // 13.3 KB

    const int U  = totals[0];
    const int u0 = blockIdx.x * 4;
    if (u0 >= U) return;
    const int u1 = min(u0 + 3, U - 1);

    // contiguous staged row range [rowlo, rowhi)
    const uint e0 = umap[u0], e1 = umap[u1];
    const int g0 = e0 >> 3, lt0 = e0 & 7;
    const int g1 = e1 >> 3, lt1 = e1 & 7;
    const int rowlo = off[g0] + lt0 * 16;
    const int rowhi = off[g1] + min(lt1 * 16 + 16, counts[g1]);
    const int nrows = rowhi - rowlo;          // <= 64

    // ---- stage x rows (coalesced dword loads) + zero pad cols 81..96 ----
    {
        const float* xb = x + (long)rowlo * C;
        const int tot = nrows * C;
        for (int i = threadIdx.x; i < tot; i += 256) {
            int r = i / C, c = i - r * C;
            xls[r * XQ_STRIDE + c] = f2b(xb[i]);
        }
        for (int i = threadIdx.x; i < nrows * 16; i += 256) {
            int r = i >> 4, c = 81 + (i & 15);
            xls[r * XQ_STRIDE + c] = 0;
        }
    }
    __syncthreads();

    const int u = u0 + (threadIdx.x >> 6);
    if (u >= U) return;
    const uint en = umap[u];
    const int g = en >> 3, lt = en & 7;
    const int N = counts[g];
    const int lane = threadIdx.x & 63;
    const int quad = lane >> 4, m16 = lane & 15;
    const bool rv = (lt * 16 + m16) < N;

    // A/B-fragments of x from LDS (ds_read_b128)
    short8 afr[3];
    const int lrow = off[g] + lt * 16 + m16 - rowlo;
    #pragma unroll
    for (int ks = 0; ks < 3; ks++) {
        if (rv) afr[ks] = *(const short8*)(xls + lrow * XQ_STRIDE + ks * 32 + quad * 8);
        else    afr[ks] = short8{0,0,0,0,0,0,0,0};
    }

    const long prow0 = (long)u * 16;

    // ---- Q, K: swapped operands (A=weights, B=x) -> row-major vector stores ----
    #pragma unroll
    for (int mat = 0; mat < 2; mat++) {
        const ushort* wT = mat ? wkT : wqT;
        const float*  bs = mat ? bk  : bq;
        ushort*      dst = mat ? Kg  : Qg;
        #pragma unroll
        for (int ct = 0; ct < 4; ct++) {
            f32x4 acc = {0.f, 0.f, 0.f, 0.f};
            #pragma unroll
            for (int ks = 0; ks < 3; ks++) {
                short8 w = *(const short8*)(wT + (ct * 16 + m16) * CP + ks * 32 + quad * 8);
                acc = MFMA16(w, afr[ks], acc);
            }
            float4 bb = *(const float4*)(bs + ct * 16 + quad * 4);
            short4v pk;
            pk[0] = (short)f2b(acc[0] + bb.x);
            pk[1] = (short)f2b(acc[1] + bb.y);
            pk[2] = (short)f2b(acc[2] + bb.z);
            pk[3] = (short)f2b(acc[3] + bb.w);
            *(short4v*)(dst + (prow0 + m16) * DK + ct * 16 + quad * 4) = pk;
        }
    }

    // ---- V: original orientation -> transposed vector stores ----
    #pragma unroll
    for (int ct = 0; ct < 4; ct++) {
        const int nn = ct * 16 + m16;
        f32x4 acc = {0.f, 0.f, 0.f, 0.f};
        #pragma unroll
        for (int ks = 0; ks < 3; ks++) {
            short8 w = *(const short8*)(wvT + nn * CP + ks * 32 + quad * 8);
            acc = MFMA16(afr[ks], w, acc);
        }
        float bval = bv[nn];
        short4v pk;
        #pragma unroll
        for (int r = 0; r < 4; r++) pk[r] = (short)f2b(acc[r] + bval);
        *(short4v*)(VTg + (long)nn * TPalloc + prow0 + quad * 4) = pk;
    }
}

// ---------- Kernel 4: attention, one wave per (group, q-tile) unit ----------
__launch_bounds__(256, 5)
__global__ void attn(const int* __restrict__ counts, const int* __restrict__ off,
                     const uint* __restrict__ umap, const int* __restrict__ totals,
                     const ushort* __restrict__ Qg, const ushort* __restrict__ Kg,
                     const ushort* __restrict__ VTg, int TPalloc,
                     const ushort* __restrict__ wuT,
                     const float* __restrict__ bu, float* __restrict__ out) {
    __shared__ __align__(16) ushort sm[4 * (16 * P_STRIDE + 16 * O_STRIDE)]; // 26.6 KB
    const int wave = threadIdx.x >> 6;
    const int u = blockIdx.x * 4 + wave;
    if (u >= totals[0]) return;
    const uint en = umap[u];
    const int g = en >> 3, qt = en & 7;
    const int N = counts[g];
    const long g16 = (long)(u - qt) * 16;
    const int lane = threadIdx.x & 63;
    const int quad = lane >> 4, m16 = lane & 15;
    const int NT8 = (N + 15) >> 4;
    const int NT4 = (N + 31) >> 5;

    short8 aq[2];
    #pragma unroll
    for (int ks = 0; ks < 2; ks++)
        aq[ks] = *(const short8*)(Qg + ((long)u * 16 + m16) * DK + ks * 32 + quad * 8);

    f32x4 sacc[8];
    #pragma unroll
    for (int ct = 0; ct < 8; ct++) if (ct < NT8) {
        f32x4 a = {0.f, 0.f, 0.f, 0.f};
        #pragma unroll
        for (int ks = 0; ks < 2; ks++) {
            short8 kb = *(const short8*)(Kg + (g16 + ct * 16 + m16) * DK +
                                         ks * 32 + quad * 8);
            a = MFMA16(aq[ks], kb, a);
        }
        sacc[ct] = a;
    }
    float mr[4] = {-3e38f, -3e38f, -3e38f, -3e38f};
    #pragma unroll
    for (int ct = 0; ct < 8; ct++) if (ct < NT8) {
        bool valid = (ct * 16 + m16) < N;
        #pragma unroll
        for (int r = 0; r < 4; r++) {
            float s = valid ? sacc[ct][r] * 0.125f : -3e38f;
            sacc[ct][r] = s;
            mr[r] = fmaxf(mr[r], s);
        }
    }
    #pragma unroll
    for (int r = 0; r < 4; r++) {
        mr[r] = fmaxf(mr[r], __shfl_xor(mr[r], 1, 64));
        mr[r] = fmaxf(mr[r], __shfl_xor(mr[r], 2, 64));
        mr[r] = fmaxf(mr[r], __shfl_xor(mr[r], 4, 64));
        mr[r] = fmaxf(mr[r], __shfl_xor(mr[r], 8, 64));
    }
    float lr[4] = {0.f, 0.f, 0.f, 0.f};
    #pragma unroll
    for (int ct = 0; ct < 8; ct++) if (ct < NT8) {
        #pragma unroll
        for (int r = 0; r < 4; r++) {
            float p = __expf(sacc[ct][r] - mr[r]);
            sacc[ct][r] = p;
            lr[r] += p;
        }
    }
    #pragma unroll
    for (int r = 0; r < 4; r++) {
        lr[r] += __shfl_xor(lr[r], 1, 64);
        lr[r] += __shfl_xor(lr[r], 2, 64);
        lr[r] += __shfl_xor(lr[r], 4, 64);
        lr[r] += __shfl_xor(lr[r], 8, 64);
    }
    ushort* P = sm + wave * (16 * P_STRIDE);
    #pragma unroll
    for (int ct = 0; ct < 8; ct++) if (ct < NT8) {
        #pragma unroll
        for (int r = 0; r < 4; r++)
            P[(quad * 4 + r) * P_STRIDE + ct * 16 + m16] = f2b(sacc[ct][r]);
    }
    if (NT8 & 1) {
        #pragma unroll
        for (int r = 0; r < 4; r++)
            P[(quad * 4 + r) * P_STRIDE + NT8 * 16 + m16] = 0;
    }
    __threadfence_block();
    short8 ap[4];
    #pragma unroll
    for (int kt = 0; kt < 4; kt++) if (kt < NT4)
        ap[kt] = *(const short8*)(P + m16 * P_STRIDE + kt * 32 + quad * 8);

    float linv[4];
    #pragma unroll
    for (int r = 0; r < 4; r++) linv[r] = (lr[r] > 0.f) ? 1.f / lr[r] : 0.f;
    ushort* O = sm + 4 * (16 * P_STRIDE) + wave * (16 * O_STRIDE);
    #pragma unroll
    for (int ot = 0; ot < 4; ot++) {
        f32x4 oa = {0.f, 0.f, 0.f, 0.f};
        #pragma unroll
        for (int kt = 0; kt < 4; kt++) if (kt < NT4) {
            short8 vb = *(const short8*)(VTg + (long)(ot * 16 + m16) * TPalloc +
                                         g16 + kt * 32 + quad * 8);
            oa = MFMA16(ap[kt], vb, oa);
        }
        #pragma unroll
        for (int r = 0; r < 4; r++)
            O[(quad * 4 + r) * O_STRIDE + ot * 16 + m16] = f2b(oa[r] * linv[r]);
    }
    __threadfence_block();
    short8 ao[2];
    #pragma unroll
    for (int ks = 0; ks < 2; ks++)
        ao[ks] = *(const short8*)(O + m16 * O_STRIDE + ks * 32 + quad * 8);

    const long obase = (long)off[g] * C;
    #pragma unroll
    for (int ct = 0; ct < 6; ct++) {
        f32x4 acc = {0.f, 0.f, 0.f, 0.f};
        #pragma unroll
        for (int ks = 0; ks < 2; ks++) {
            short8 wb = *(const short8*)(wuT + (ct * 16 + m16) * DK + ks * 32 + quad * 8);
            acc = MFMA16(ao[ks], wb, acc);
        }
        int e = ct * 16 + m16;
        if (e < C) {
            float bue = bu[e];
            #pragma unroll
            for (int r = 0; r < 4; r++) {
                int row = qt * 16 + quad * 4 + r;
                if (row < N) out[obase + (long)row * C + e] = acc[r] + bue;
            }
        }
    }
}

// ---------- launch ----------
extern "C" void kernel_launch(void* const* d_in, const int* in_sizes, int n_in,
                              void* d_out, int out_size, void* d_ws, size_t ws_size,
                              hipStream_t stream) {
    const float* x      = (const float*)d_in[0];
    const int*   counts = (const int*)  d_in[1];
    const float* prior  = (const float*)d_in[2];
    const float* wq     = (const float*)d_in[3];
    const float* bq     = (const float*)d_in[4];
    const float* wk     = (const float*)d_in[5];
    const float* bk     = (const float*)d_in[6];
    const float* wv     = (const float*)d_in[7];
    const float* bv     = (const float*)d_in[8];
    const float* wu     = (const float*)d_in[9];
    const float* bu     = (const float*)d_in[10];
    float* out = (float*)d_out;

    const int B     = in_sizes[1];
    const int total = in_sizes[0] / C;
    const int umax  = (total + 15 * B + 15) / 16;    // upper bound on Σceil(N/16)
    const int TPalloc = ((umax * 16 + 32 + 15) / 16) * 16;

    char* p = (char*)d_ws;
    auto alloc = [&](size_t bytes) {
        void* r = (void*)p;
        p += (bytes + 255) & ~(size_t)255;
        return r;
    };
    int*    off    = (int*)   alloc((size_t)(B + 1) * 4);
    int*    totals = (int*)   alloc(4);
    uint*   umap   = (uint*)  alloc((size_t)umax * 4);
    ushort* wqT    = (ushort*)alloc((size_t)DK * CP * 2);
    ushort* wkT    = (ushort*)alloc((size_t)DK * CP * 2);
    ushort* wvT    = (ushort*)alloc((size_t)DK * CP * 2);
    ushort* wuT    = (ushort*)alloc((size_t)CP * DK * 2);
    ushort* Qg     = (ushort*)alloc((size_t)umax * 16 * DK * 2);
    ushort* Kg     = (ushort*)alloc((size_t)umax * 16 * DK * 2);
    ushort* VTg    = (ushort*)alloc((size_t)DK * TPalloc * 2);

    const int ublocks = (umax + 3) / 4;

    scan_build<<<1, 256, 0, stream>>>(counts, B, off, umap, totals);
    prep_weights<<<(4 * DK * CP + 255) / 256, 256, 0, stream>>>(
        prior, wq, wk, wv, wu, wqT, wkT, wvT, wuT);
    qkv_proj<<<ublocks, 256, 0, stream>>>(x, counts, off, umap, totals,
                                          wqT, wkT, wvT, bq, bk, bv,
                                          Qg, Kg, VTg, TPalloc);
    attn<<<ublocks, 256, 0, stream>>>(counts, off, umap, totals,
                                      Qg, Kg, VTg, TPalloc, wuT, bu, out);
}